// Round 5
// baseline (232.333 us; speedup 1.0000x reference)
//
#include <hip/hip_runtime.h>
#include <hip/hip_bf16.h>

#define DEVI __device__ __forceinline__

typedef __attribute__((ext_vector_type(8))) _Float16 f16x8;
typedef __attribute__((ext_vector_type(4))) float f32x4;
typedef __attribute__((ext_vector_type(4))) unsigned short us4;

#define VMW(N) asm volatile("s_waitcnt vmcnt(" #N ")" ::: "memory")
DEVI void sbar() {
  asm volatile("" ::: "memory");
  __builtin_amdgcn_s_barrier();
  asm volatile("" ::: "memory");
}

DEVI unsigned short f2h(float f) {
  union { _Float16 h; unsigned short u; } v;
  v.h = (_Float16)f;
  return v.u;
}

// ---------------- elementwise convert x -> fp16 ----------------
__global__ void __launch_bounds__(256) k_convert_f16(
    const float* __restrict__ x, unsigned short* __restrict__ o, int n4) {
  int i = blockIdx.x * 256 + threadIdx.x;
  if (i >= n4) return;
  float4 v = reinterpret_cast<const float4*>(x)[i];
  us4 h;
  h[0] = f2h(v.x); h[1] = f2h(v.y); h[2] = f2h(v.z); h[3] = f2h(v.w);
  reinterpret_cast<us4*>(o)[i] = h;
}

// ---------------- transpose weight [K][N] -> WT[N][K] fp16 ----------------
__global__ void __launch_bounds__(256) k_transpose_f16(
    const float* __restrict__ W, unsigned short* __restrict__ T, int n) {
  __shared__ float t[32][33];
  int tx = threadIdx.x & 31, ty = threadIdx.x >> 5;
  int n0 = blockIdx.x * 32, k0 = blockIdx.y * 32;
#pragma unroll
  for (int r = 0; r < 4; ++r)
    t[ty + r * 8][tx] = W[(size_t)(k0 + ty + r * 8) * n + n0 + tx];
  __syncthreads();
#pragma unroll
  for (int r = 0; r < 4; ++r) {
    int nn = n0 + ty + r * 8;
    T[(size_t)nn * n + k0 + tx] = f2h(t[tx][ty + r * 8]);
  }
}

// ---------------- pipelined GEMM: C[M][N] = A[M][K] * B_T[N][K] (fp16) -------
// Tile 256x128, BK=64, 512 threads = 8 waves (4M x 2N, per-wave 64x64 out).
// LDS: 3 buffers x (A 256x64 + B 128x64) fp16 = 144 KB, XOR-swizzled.
// Pipeline: tile t staged 2 iterations ahead; s_waitcnt vmcnt(12) (counted,
// never 0 in steady state) + raw s_barrier. 6 global_load_lds per stage.
DEVI void stageA(unsigned short* lbase, const unsigned short* g, int ldg, int tid) {
#pragma unroll
  for (int it = 0; it < 4; ++it) {
    int chunk = it * 512 + tid;
    int r = chunk >> 3, s = chunk & 7;
    int c = (s ^ (r & 7)) * 8;
    const unsigned short* gp = g + (size_t)r * ldg + c;
    unsigned short* lp = lbase + (it * 512 + (tid & ~63)) * 8;  // wave-uniform
    __builtin_amdgcn_global_load_lds(
        (const __attribute__((address_space(1))) unsigned int*)gp,
        (__attribute__((address_space(3))) unsigned int*)lp, 16, 0, 0);
  }
}
DEVI void stageB(unsigned short* lbase, const unsigned short* g, int ldg, int tid) {
#pragma unroll
  for (int it = 0; it < 2; ++it) {
    int chunk = it * 512 + tid;
    int r = chunk >> 3, s = chunk & 7;
    int c = (s ^ (r & 7)) * 8;
    const unsigned short* gp = g + (size_t)r * ldg + c;
    unsigned short* lp = lbase + (it * 512 + (tid & ~63)) * 8;
    __builtin_amdgcn_global_load_lds(
        (const __attribute__((address_space(1))) unsigned int*)gp,
        (__attribute__((address_space(3))) unsigned int*)lp, 16, 0, 0);
  }
}

DEVI f16x8 frag(const unsigned short* base, int row, int kk, int lr) {
  int slot = (kk * 4 + lr) ^ (row & 7);
  return *reinterpret_cast<const f16x8*>(base + row * 64 + slot * 8);
}

// EPI: 0 = QKV fused: bias + fp16 q/k rows, fp16 v transposed to v_t[b][d][s]
//      2 = write fp32 (scores, z-strided)
//      3 = write fp16 (attn = P*V, z-strided)
//      4 = bias + residual + write fp32 (out proj)
template <int EPI>
__global__ void __launch_bounds__(512, 2) k_gemm(
    const unsigned short* __restrict__ A, const unsigned short* __restrict__ B,
    int nt, int ldA, int ldB,
    size_t azs, size_t bzs, size_t czs,
    const float* __restrict__ b0, const float* __restrict__ b1,
    const float* __restrict__ b2, const float* __restrict__ resid,
    float* __restrict__ outF, unsigned short* __restrict__ o0,
    unsigned short* __restrict__ o1, unsigned short* __restrict__ o2, int ldc) {
  __shared__ unsigned short lds[3 * 24576];  // 144 KB

  // bijective chunked XCD swizzle (all launch grids have nwg % 8 == 0)
  const int gx = gridDim.x, gy = gridDim.y;
  const int nwg = gx * gy * gridDim.z;
  const int l = (blockIdx.z * gy + blockIdx.y) * gx + blockIdx.x;
  const int nl = (l & 7) * (nwg >> 3) + (l >> 3);
  const int bx = nl % gx;
  const int rem = nl / gx;
  const int by = rem % gy;
  const int z = rem / gy;

  const int tid = threadIdx.x, lane = tid & 63, wid = tid >> 6;
  const int wr = (wid >> 1) * 64, wc = (wid & 1) * 64;
  const int lc = lane & 15, lr = lane >> 4;
  const size_t row0 = (size_t)bx * 256, col0 = (size_t)by * 128;

  const unsigned short* Ag = A + (size_t)z * azs + row0 * ldA;
  const unsigned short* Bg = B + (size_t)z * bzs + col0 * ldB;

  f32x4 acc[4][4] = {};

  // prologue: stage tiles 0,1 into buffers 0,1  (12 loads outstanding)
  stageA(lds, Ag, ldA, tid);
  stageB(lds + 16384, Bg, ldB, tid);
  stageA(lds + 24576, Ag + 64, ldA, tid);
  stageB(lds + 24576 + 16384, Bg + 64, ldB, tid);

  for (int t = 0; t < nt; ++t) {
    unsigned short* cur = lds + (t % 3) * 24576;
    if (t + 2 < nt) {
      unsigned short* nx = lds + ((t + 2) % 3) * 24576;
      stageA(nx, Ag + (size_t)(t + 2) * 64, ldA, tid);
      stageB(nx + 16384, Bg + (size_t)(t + 2) * 64, ldB, tid);
      VMW(12);                 // tile t's 6 loads (issued 2 iters ago) done
    } else if (t + 1 < nt) {
      VMW(6);
    } else {
      VMW(0);
    }
    sbar();
#pragma unroll
    for (int kk = 0; kk < 2; ++kk) {
      f16x8 af[4], bf[4];
#pragma unroll
      for (int i = 0; i < 4; ++i) {
        af[i] = frag(cur, wr + i * 16 + lc, kk, lr);
        bf[i] = frag(cur + 16384, wc + i * 16 + lc, kk, lr);
      }
#pragma unroll
      for (int mi = 0; mi < 4; ++mi)
#pragma unroll
        for (int ni = 0; ni < 4; ++ni)
          acc[mi][ni] = __builtin_amdgcn_mfma_f32_16x16x32_f16(af[mi], bf[ni], acc[mi][ni], 0, 0, 0);
    }
    sbar();
  }

#pragma unroll
  for (int mi = 0; mi < 4; ++mi) {
#pragma unroll
    for (int ni = 0; ni < 4; ++ni) {
      const int r0 = (int)row0 + wr + mi * 16 + lr * 4;
      const int c = (int)col0 + wc + ni * 16 + lc;
      f32x4 a = acc[mi][ni];
      if (EPI == 0) {
        // QKV fused: whole tile lies in one of q/k/v (1024 % 128 == 0)
        const int sub = (int)(col0 >> 10);
        const int cc = c & 1023;
        if (sub == 0) {
          float b = b0[cc];
#pragma unroll
          for (int r = 0; r < 4; ++r)
            o0[(size_t)(r0 + r) * 1024 + cc] = f2h(a[r] + b);
        } else if (sub == 1) {
          float b = b1[cc];
#pragma unroll
          for (int r = 0; r < 4; ++r)
            o1[(size_t)(r0 + r) * 1024 + cc] = f2h(a[r] + b);
        } else {
          float b = b2[cc];
          us4 pk;
#pragma unroll
          for (int r = 0; r < 4; ++r) pk[r] = f2h(a[r] + b);
          // v_t[b][d=cc][s]: 4 consecutive s at fixed d
          *reinterpret_cast<us4*>(o2 + ((size_t)(r0 >> 11) * 1024 + cc) * 2048 + (r0 & 2047)) = pk;
        }
      } else if (EPI == 2) {
#pragma unroll
        for (int r = 0; r < 4; ++r)
          outF[(size_t)z * czs + (size_t)(r0 + r) * ldc + c] = a[r];
      } else if (EPI == 3) {
#pragma unroll
        for (int r = 0; r < 4; ++r)
          o0[(size_t)z * czs + (size_t)(r0 + r) * ldc + c] = f2h(a[r]);
      } else {
        float b = b0[c];
#pragma unroll
        for (int r = 0; r < 4; ++r) {
          size_t idx = (size_t)(r0 + r) * ldc + c;
          outF[idx] = a[r] + b + resid[idx];
        }
      }
    }
  }
}

// ---------------- row softmax: scores fp32 [rows][2048] -> P fp16 IN-PLACE ----
__global__ void __launch_bounds__(256) k_softmax(
    const float* __restrict__ S, unsigned short* __restrict__ P) {
  __shared__ float red[4];
  const int row = blockIdx.x, tid = threadIdx.x;
  const int lane = tid & 63, wid = tid >> 6;
  const float* src = S + (size_t)row * 2048;
  float4 v0 = *reinterpret_cast<const float4*>(src + tid * 8);
  float4 v1 = *reinterpret_cast<const float4*>(src + tid * 8 + 4);
  float vv[8] = {v0.x, v0.y, v0.z, v0.w, v1.x, v1.y, v1.z, v1.w};
  float m = vv[0];
#pragma unroll
  for (int j = 1; j < 8; ++j) m = fmaxf(m, vv[j]);
#pragma unroll
  for (int o = 32; o > 0; o >>= 1) m = fmaxf(m, __shfl_xor(m, o));
  if (lane == 0) red[wid] = m;
  __syncthreads();
  m = fmaxf(fmaxf(red[0], red[1]), fmaxf(red[2], red[3]));
  __syncthreads();
  float e[8];
  float s = 0.f;
#pragma unroll
  for (int j = 0; j < 8; ++j) { e[j] = __expf(vv[j] - m); s += e[j]; }
#pragma unroll
  for (int o = 32; o > 0; o >>= 1) s += __shfl_xor(s, o);
  if (lane == 0) red[wid] = s;
  __syncthreads();
  s = red[0] + red[1] + red[2] + red[3];
  float inv = 1.0f / s;
  us4 p0, p1;
#pragma unroll
  for (int j = 0; j < 4; ++j) p0[j] = f2h(e[j] * inv);
#pragma unroll
  for (int j = 0; j < 4; ++j) p1[j] = f2h(e[j + 4] * inv);
  // P rows live at 4096-element (8192 B) stride inside the scores buffer
  us4* dst = reinterpret_cast<us4*>(P + (size_t)row * 4096 + tid * 8);
  dst[0] = p0;
  dst[1] = p1;
}

extern "C" void kernel_launch(void* const* d_in, const int* in_sizes, int n_in,
                              void* d_out, int out_size, void* d_ws, size_t ws_size,
                              hipStream_t stream) {
  (void)in_sizes; (void)n_in; (void)out_size; (void)ws_size;
  const float* x  = (const float*)d_in[0];
  const float* Wq = (const float*)d_in[1];
  const float* bq = (const float*)d_in[2];
  const float* Wk = (const float*)d_in[3];
  const float* bk = (const float*)d_in[4];
  const float* Wv = (const float*)d_in[5];
  const float* bv = (const float*)d_in[6];
  const float* Wo = (const float*)d_in[7];
  const float* bo = (const float*)d_in[8];
  float* out = (float*)d_out;

  char* p = (char*)d_ws;
  auto take = [&](size_t bytes) {
    char* r = p;
    p += (bytes + 255) & ~(size_t)255;
    return r;
  };
  const size_t SD = (size_t)4 * 2048 * 1024;  // 8388608 elements
  unsigned short* x_h   = (unsigned short*)take(SD * 2);
  unsigned short* q_h   = (unsigned short*)take(SD * 2);
  unsigned short* k_h   = (unsigned short*)take(SD * 2);
  unsigned short* WqkvT = (unsigned short*)take((size_t)3072 * 1024 * 2);
  unsigned short* WoT   = (unsigned short*)take((size_t)1024 * 1024 * 2);
  unsigned short* v_t   = (unsigned short*)take(SD * 2);   // [B][D][S] fp16
  unsigned short* attn  = (unsigned short*)take(SD * 2);   // [B*S][D] fp16
  const size_t SC_B = (size_t)2048 * 2048;  // score elements per batch
  float* scores = (float*)take(4 * SC_B * 4);  // P fp16 aliased in-place

  dim3 blk(256), blk5(512);
  k_convert_f16<<<dim3(8192), blk, 0, stream>>>(x, x_h, (int)(SD / 4));
  k_transpose_f16<<<dim3(32, 32), blk, 0, stream>>>(Wq, WqkvT, 1024);
  k_transpose_f16<<<dim3(32, 32), blk, 0, stream>>>(Wk, WqkvT + (size_t)1024 * 1024, 1024);
  k_transpose_f16<<<dim3(32, 32), blk, 0, stream>>>(Wv, WqkvT + (size_t)2048 * 1024, 1024);
  k_transpose_f16<<<dim3(32, 32), blk, 0, stream>>>(Wo, WoT, 1024);

  // fused QKV projection: [8192 x 1024] x [3072 x 1024]^T
  k_gemm<0><<<dim3(32, 24, 1), blk5, 0, stream>>>(
      x_h, WqkvT, 16, 1024, 1024, 0, 0, 0,
      bq, bk, bv, nullptr, nullptr, q_h, k_h, v_t, 0);

  const size_t QZS = (size_t)2048 * 1024;   // q/k batch stride (elements)
  const size_t VZS = (size_t)1024 * 2048;   // v_t batch stride
  const size_t PZS = SC_B * 2;              // P batch stride (fp16, aliased rows)
  // scores = q . k^T  (fp32 out), all 4 batches
  k_gemm<2><<<dim3(8, 16, 4), blk5, 0, stream>>>(
      q_h, k_h, 16, 1024, 1024, QZS, QZS, SC_B,
      nullptr, nullptr, nullptr, nullptr, scores, nullptr, nullptr, nullptr, 2048);
  // softmax in-place (P fp16 overwrites score rows)
  k_softmax<<<dim3(8192), blk, 0, stream>>>(scores, (unsigned short*)scores);
  // attn = P . V   (P has ldA=4096 fp16 elements due to in-place aliasing)
  k_gemm<3><<<dim3(8, 8, 4), blk5, 0, stream>>>(
      (const unsigned short*)scores, v_t, 32, 4096, 2048, PZS, VZS, QZS,
      nullptr, nullptr, nullptr, nullptr, nullptr, attn, nullptr, nullptr, 1024);
  // out = attn . Wo^T + bo + x
  k_gemm<4><<<dim3(32, 8, 1), blk5, 0, stream>>>(
      attn, WoT, 16, 1024, 1024, 0, 0, 0,
      bo, nullptr, nullptr, x, out, nullptr, nullptr, nullptr, 1024);
}

// Round 6
// 224.137 us; speedup vs baseline: 1.0366x; 1.0366x over previous
//
#include <hip/hip_runtime.h>
#include <hip/hip_bf16.h>

#define DEVI __device__ __forceinline__

typedef __attribute__((ext_vector_type(8))) _Float16 f16x8;
typedef __attribute__((ext_vector_type(4))) float f32x4;
typedef __attribute__((ext_vector_type(4))) unsigned short us4;

#define VMW(N) asm volatile("s_waitcnt vmcnt(" #N ")" ::: "memory")
DEVI void sbar() {
  asm volatile("" ::: "memory");
  __builtin_amdgcn_s_barrier();
  asm volatile("" ::: "memory");
}

DEVI unsigned short f2h(float f) {
  union { _Float16 h; unsigned short u; } v;
  v.h = (_Float16)f;
  return v.u;
}

// ---------------- elementwise convert x -> fp16 ----------------
__global__ void __launch_bounds__(256) k_convert_f16(
    const float* __restrict__ x, unsigned short* __restrict__ o, int n4) {
  int i = blockIdx.x * 256 + threadIdx.x;
  if (i >= n4) return;
  float4 v = reinterpret_cast<const float4*>(x)[i];
  us4 h;
  h[0] = f2h(v.x); h[1] = f2h(v.y); h[2] = f2h(v.z); h[3] = f2h(v.w);
  reinterpret_cast<us4*>(o)[i] = h;
}

// ---------------- transpose weight [K][N] -> WT[N][K] fp16 ----------------
__global__ void __launch_bounds__(256) k_transpose_f16(
    const float* __restrict__ W, unsigned short* __restrict__ T, int n) {
  __shared__ float t[32][33];
  int tx = threadIdx.x & 31, ty = threadIdx.x >> 5;
  int n0 = blockIdx.x * 32, k0 = blockIdx.y * 32;
#pragma unroll
  for (int r = 0; r < 4; ++r)
    t[ty + r * 8][tx] = W[(size_t)(k0 + ty + r * 8) * n + n0 + tx];
  __syncthreads();
#pragma unroll
  for (int r = 0; r < 4; ++r) {
    int nn = n0 + ty + r * 8;
    T[(size_t)nn * n + k0 + tx] = f2h(t[tx][ty + r * 8]);
  }
}

// ---------------- shared helpers ----------------
DEVI void gload16(const unsigned short* gp, unsigned short* lp) {
  __builtin_amdgcn_global_load_lds(
      (const __attribute__((address_space(1))) unsigned int*)gp,
      (__attribute__((address_space(3))) unsigned int*)lp, 16, 0, 0);
}

// XOR-swizzled fragment read (conflict-free ds_read_b128)
DEVI f16x8 frag(const unsigned short* base, int row, int kk, int lr) {
  int slot = (kk * 4 + lr) ^ (row & 7);
  return *reinterpret_cast<const f16x8*>(base + row * 64 + slot * 8);
}

// =====================================================================
// 8-phase 256x256 GEMM (T2+T3+T4+T5), BK=64, 512 threads = 8 waves (2Mx4N).
// Per-wave out 128x64 (acc[8][4]). LDS = 8 half-tile slots (128 rows x 64 K
// f16, swizzled) = 128 KiB: SA(d,h), SB(d,h), d = K-tile parity, h = half.
// Per K-tile 4 phases: B frags hoisted at phase 0; phases interleave
// {stage half-tile | ds_read | barrier | lgkm0 | setprio 16xMFMA | barrier}.
// Counted vmcnt(4) only at phase-3/phase-7 ends (never 0 mid-loop).
// Staging: p0->S1A(k+64), p1->S0B(k+128), p4->S0A(k+128), p5->S1B(k+192).
// =====================================================================
DEVI void stage_half(unsigned short* lbase, const unsigned short* g, int ldg, int tid) {
#pragma unroll
  for (int it = 0; it < 2; ++it) {
    int chunk = it * 512 + tid;
    int r = chunk >> 3, s = chunk & 7;
    int c = (s ^ (r & 7)) * 8;
    gload16(g + (size_t)r * ldg + c, lbase + (it * 512 + (tid & ~63)) * 8);
  }
}

#define PHASE(AB, BB, MI0, READB, STAGE_STMT, ENDVM)                          \
  {                                                                           \
    STAGE_STMT;                                                               \
    if (READB) {                                                              \
      _Pragma("unroll") for (int ni = 0; ni < 4; ++ni)                        \
          _Pragma("unroll") for (int kk = 0; kk < 2; ++kk)                    \
              b[ni][kk] = frag((BB), (wid & 1) * 64 + ni * 16 + lc, kk, lr);  \
    }                                                                         \
    f16x8 a00 = frag((AB), (MI0) * 16 + lc, 0, lr);                           \
    f16x8 a01 = frag((AB), (MI0) * 16 + lc, 1, lr);                           \
    f16x8 a10 = frag((AB), (MI0 + 1) * 16 + lc, 0, lr);                       \
    f16x8 a11 = frag((AB), (MI0 + 1) * 16 + lc, 1, lr);                       \
    sbar();                                                                   \
    asm volatile("s_waitcnt lgkmcnt(0)" ::: "memory");                        \
    __builtin_amdgcn_sched_barrier(0);                                        \
    __builtin_amdgcn_s_setprio(1);                                            \
    _Pragma("unroll") for (int ni = 0; ni < 4; ++ni) {                        \
      acc[MI0][ni] = __builtin_amdgcn_mfma_f32_16x16x32_f16(a00, b[ni][0], acc[MI0][ni], 0, 0, 0);             \
      acc[MI0][ni] = __builtin_amdgcn_mfma_f32_16x16x32_f16(a01, b[ni][1], acc[MI0][ni], 0, 0, 0);             \
      acc[MI0 + 1][ni] = __builtin_amdgcn_mfma_f32_16x16x32_f16(a10, b[ni][0], acc[MI0 + 1][ni], 0, 0, 0);     \
      acc[MI0 + 1][ni] = __builtin_amdgcn_mfma_f32_16x16x32_f16(a11, b[ni][1], acc[MI0 + 1][ni], 0, 0, 0);     \
    }                                                                         \
    __builtin_amdgcn_s_setprio(0);                                            \
    ENDVM;                                                                    \
    sbar();                                                                   \
  }

// EPI: 0 = QKV fused epilogue (bias; q,k row-major fp16; v transposed v_t)
//      2 = write fp32 (scores, z-strided)
template <int EPI>
__global__ void __launch_bounds__(512, 1) k_gemm8(
    const unsigned short* __restrict__ A, const unsigned short* __restrict__ B,
    int nt2, int ldA, int ldB, size_t azs, size_t bzs, size_t czs,
    const float* __restrict__ b0, const float* __restrict__ b1,
    const float* __restrict__ b2,
    float* __restrict__ outF, unsigned short* __restrict__ o0,
    unsigned short* __restrict__ o1, unsigned short* __restrict__ o2, int ldc) {
  __shared__ __align__(16) unsigned short lds[65536];  // 128 KiB

  // bijective chunked XCD swizzle (grids are multiples of 8)
  const int gx = gridDim.x, gy = gridDim.y;
  const int nwg = gx * gy * gridDim.z;
  const int l = (blockIdx.z * gy + blockIdx.y) * gx + blockIdx.x;
  const int nl = (l & 7) * (nwg >> 3) + (l >> 3);
  const int bx = nl % gx;
  const int rem = nl / gx;
  const int by = rem % gy;
  const int z = rem / gy;

  const int tid = threadIdx.x, lane = tid & 63, wid = tid >> 6;
  const int lc = lane & 15, lr = lane >> 4;
  const int ha = wid >> 2;        // which A half this wave consumes
  const int hb = (wid & 3) >> 1;  // which B half
  const size_t row0 = (size_t)bx * 256, col0 = (size_t)by * 256;

  unsigned short* SA00 = lds;
  unsigned short* SA01 = lds + 8192;
  unsigned short* SA10 = lds + 16384;
  unsigned short* SA11 = lds + 24576;
  unsigned short* SB00 = lds + 32768;
  unsigned short* SB01 = lds + 40960;
  unsigned short* SB10 = lds + 49152;
  unsigned short* SB11 = lds + 57344;

  const unsigned short* Ag0 = A + (size_t)z * azs + row0 * ldA;
  const unsigned short* Ag1 = Ag0 + (size_t)128 * ldA;
  const unsigned short* Bg0 = B + (size_t)z * bzs + col0 * ldB;
  const unsigned short* Bg1 = Bg0 + (size_t)128 * ldB;

  const unsigned short* Ab0 = SA00 + ha * 8192;
  const unsigned short* Ab1 = SA10 + ha * 8192;
  const unsigned short* Bb0 = SB00 + hb * 8192;
  const unsigned short* Bb1 = SB10 + hb * 8192;

  f32x4 acc[8][4] = {};
  f16x8 b[4][2];

  // prologue: S0A, S0B (k=0), S1B (k=64) -> 12 loads/thread; need first 8 done
  stage_half(SA00, Ag0, ldA, tid);
  stage_half(SA01, Ag1, ldA, tid);
  stage_half(SB00, Bg0, ldB, tid);
  stage_half(SB01, Bg1, ldB, tid);
  stage_half(SB10, Bg0 + 64, ldB, tid);
  stage_half(SB11, Bg1 + 64, ldB, tid);
  VMW(4);
  sbar();

  for (int t = 0; t < nt2; ++t) {
    const int kb = t << 7;
    const bool more = (t + 1 < nt2);
    // ---- K-tile 2t (d=0 slots) ----
    PHASE(Ab0, Bb0, 0, true,
          { stage_half(SA10, Ag0 + kb + 64, ldA, tid);
            stage_half(SA11, Ag1 + kb + 64, ldA, tid); },
          {});
    PHASE(Ab0, Bb0, 2, false,
          { if (more) { stage_half(SB00, Bg0 + kb + 128, ldB, tid);
                        stage_half(SB01, Bg1 + kb + 128, ldB, tid); } },
          {});
    PHASE(Ab0, Bb0, 4, false, {}, {});
    PHASE(Ab0, Bb0, 6, false, {},
          { if (more) { VMW(4); } else { VMW(0); } });
    // ---- K-tile 2t+1 (d=1 slots) ----
    PHASE(Ab1, Bb1, 0, true,
          { if (more) { stage_half(SA00, Ag0 + kb + 128, ldA, tid);
                        stage_half(SA01, Ag1 + kb + 128, ldA, tid); } },
          {});
    PHASE(Ab1, Bb1, 2, false,
          { if (more) { stage_half(SB10, Bg0 + kb + 192, ldB, tid);
                        stage_half(SB11, Bg1 + kb + 192, ldB, tid); } },
          {});
    PHASE(Ab1, Bb1, 4, false, {}, {});
    PHASE(Ab1, Bb1, 6, false, {},
          { if (more) { VMW(4); } });
  }

#pragma unroll
  for (int mi = 0; mi < 8; ++mi) {
#pragma unroll
    for (int ni = 0; ni < 4; ++ni) {
      const int r0 = (int)row0 + (wid >> 2) * 128 + mi * 16 + lr * 4;
      const int c = (int)col0 + (wid & 3) * 64 + ni * 16 + lc;
      f32x4 a = acc[mi][ni];
      if (EPI == 0) {
        const int sub = c >> 10;  // tile never spans q/k/v boundary
        const int cc = c & 1023;
        if (sub == 0) {
          float bb = b0[cc];
#pragma unroll
          for (int r = 0; r < 4; ++r)
            o0[(size_t)(r0 + r) * 1024 + cc] = f2h(a[r] + bb);
        } else if (sub == 1) {
          float bb = b1[cc];
#pragma unroll
          for (int r = 0; r < 4; ++r)
            o1[(size_t)(r0 + r) * 1024 + cc] = f2h(a[r] + bb);
        } else {
          float bb = b2[cc];
          us4 pk;
#pragma unroll
          for (int r = 0; r < 4; ++r) pk[r] = f2h(a[r] + bb);
          // v_t[b][d=cc][s], 4 consecutive s
          *reinterpret_cast<us4*>(o2 + ((size_t)(r0 >> 11) * 1024 + cc) * 2048 + (r0 & 2047)) = pk;
        }
      } else {
#pragma unroll
        for (int r = 0; r < 4; ++r)
          outF[(size_t)z * czs + (size_t)(r0 + r) * ldc + c] = a[r];
      }
    }
  }
}

// =====================================================================
// small 128x128 GEMM (round-4 proven, 4 blocks/CU) for PV and out-proj
// =====================================================================
DEVI void stage_tile64s(unsigned short* lbase, const unsigned short* g, int ldg,
                        int wid, int lane) {
#pragma unroll
  for (int it = 0; it < 4; ++it) {
    int chunk = it * 256 + wid * 64 + lane;
    int r = chunk >> 3, s = chunk & 7;
    int c = (s ^ (r & 7)) * 8;
    gload16(g + (size_t)r * ldg + c, lbase + (it * 256 + wid * 64) * 8);
  }
}

// EPI: 3 = write fp16 (attn = P*V, z-strided); 4 = bias+residual fp32
template <int EPI>
__global__ void __launch_bounds__(256, 4) k_gemm_s(
    const unsigned short* __restrict__ A, const unsigned short* __restrict__ B,
    int K, int ldA, int ldB,
    size_t azs, size_t bzs, size_t czs,
    const float* __restrict__ bias, const float* __restrict__ resid,
    float* __restrict__ outF, unsigned short* __restrict__ outH, int ldc) {
  __shared__ unsigned short lds[2 * 8192];
  unsigned short* Alds = lds;
  unsigned short* Blds = lds + 8192;

  const int gx = gridDim.x, gy = gridDim.y;
  const int nwg = gx * gy * gridDim.z;
  const int l = (blockIdx.z * gy + blockIdx.y) * gx + blockIdx.x;
  const int nl = (l & 7) * (nwg >> 3) + (l >> 3);
  const int bx = nl % gx;
  const int rem = nl / gx;
  const int by = rem % gy;
  const int z = rem / gy;

  const int tid = threadIdx.x, lane = tid & 63, wid = tid >> 6;
  const int wr = (wid >> 1) * 64, wc = (wid & 1) * 64;
  const int lc = lane & 15, lr = lane >> 4;
  const size_t row0 = (size_t)bx * 128, col0 = (size_t)by * 128;

  const unsigned short* Ag = A + (size_t)z * azs + row0 * ldA;
  const unsigned short* Bg = B + (size_t)z * bzs + col0 * ldB;

  f32x4 acc[4][4] = {};

  for (int k0 = 0; k0 < K; k0 += 64) {
    stage_tile64s(Alds, Ag + k0, ldA, wid, lane);
    stage_tile64s(Blds, Bg + k0, ldB, wid, lane);
    __syncthreads();
#pragma unroll
    for (int kk = 0; kk < 2; ++kk) {
      f16x8 af[4], bf[4];
#pragma unroll
      for (int i = 0; i < 4; ++i) {
        af[i] = frag(Alds, wr + i * 16 + lc, kk, lr);
        bf[i] = frag(Blds, wc + i * 16 + lc, kk, lr);
      }
#pragma unroll
      for (int mi = 0; mi < 4; ++mi)
#pragma unroll
        for (int ni = 0; ni < 4; ++ni)
          acc[mi][ni] = __builtin_amdgcn_mfma_f32_16x16x32_f16(af[mi], bf[ni], acc[mi][ni], 0, 0, 0);
    }
    __syncthreads();
  }

#pragma unroll
  for (int mi = 0; mi < 4; ++mi) {
#pragma unroll
    for (int ni = 0; ni < 4; ++ni) {
      const int r0 = (int)row0 + wr + mi * 16 + lr * 4;
      const int c = (int)col0 + wc + ni * 16 + lc;
      f32x4 a = acc[mi][ni];
      if (EPI == 3) {
#pragma unroll
        for (int r = 0; r < 4; ++r)
          outH[(size_t)z * czs + (size_t)(r0 + r) * ldc + c] = f2h(a[r]);
      } else {
        float b = bias[c];
#pragma unroll
        for (int r = 0; r < 4; ++r) {
          size_t idx = (size_t)(r0 + r) * ldc + c;
          outF[idx] = a[r] + b + resid[idx];
        }
      }
    }
  }
}

// ---------------- row softmax: scores fp32 [rows][2048] -> P fp16 IN-PLACE ----
__global__ void __launch_bounds__(256) k_softmax(
    const float* __restrict__ S, unsigned short* __restrict__ P) {
  __shared__ float red[4];
  const int row = blockIdx.x, tid = threadIdx.x;
  const int lane = tid & 63, wid = tid >> 6;
  const float* src = S + (size_t)row * 2048;
  float4 v0 = *reinterpret_cast<const float4*>(src + tid * 8);
  float4 v1 = *reinterpret_cast<const float4*>(src + tid * 8 + 4);
  float vv[8] = {v0.x, v0.y, v0.z, v0.w, v1.x, v1.y, v1.z, v1.w};
  float m = vv[0];
#pragma unroll
  for (int j = 1; j < 8; ++j) m = fmaxf(m, vv[j]);
#pragma unroll
  for (int o = 32; o > 0; o >>= 1) m = fmaxf(m, __shfl_xor(m, o));
  if (lane == 0) red[wid] = m;
  __syncthreads();
  m = fmaxf(fmaxf(red[0], red[1]), fmaxf(red[2], red[3]));
  __syncthreads();
  float e[8];
  float s = 0.f;
#pragma unroll
  for (int j = 0; j < 8; ++j) { e[j] = __expf(vv[j] - m); s += e[j]; }
#pragma unroll
  for (int o = 32; o > 0; o >>= 1) s += __shfl_xor(s, o);
  if (lane == 0) red[wid] = s;
  __syncthreads();
  s = red[0] + red[1] + red[2] + red[3];
  float inv = 1.0f / s;
  us4 p0, p1;
#pragma unroll
  for (int j = 0; j < 4; ++j) p0[j] = f2h(e[j] * inv);
#pragma unroll
  for (int j = 0; j < 4; ++j) p1[j] = f2h(e[j + 4] * inv);
  us4* dst = reinterpret_cast<us4*>(P + (size_t)row * 4096 + tid * 8);
  dst[0] = p0;
  dst[1] = p1;
}

extern "C" void kernel_launch(void* const* d_in, const int* in_sizes, int n_in,
                              void* d_out, int out_size, void* d_ws, size_t ws_size,
                              hipStream_t stream) {
  (void)in_sizes; (void)n_in; (void)out_size; (void)ws_size;
  const float* x  = (const float*)d_in[0];
  const float* Wq = (const float*)d_in[1];
  const float* bq = (const float*)d_in[2];
  const float* Wk = (const float*)d_in[3];
  const float* bk = (const float*)d_in[4];
  const float* Wv = (const float*)d_in[5];
  const float* bv = (const float*)d_in[6];
  const float* Wo = (const float*)d_in[7];
  const float* bo = (const float*)d_in[8];
  float* out = (float*)d_out;

  char* p = (char*)d_ws;
  auto take = [&](size_t bytes) {
    char* r = p;
    p += (bytes + 255) & ~(size_t)255;
    return r;
  };
  const size_t SD = (size_t)4 * 2048 * 1024;  // 8388608 elements
  unsigned short* x_h   = (unsigned short*)take(SD * 2);
  unsigned short* q_h   = (unsigned short*)take(SD * 2);
  unsigned short* k_h   = (unsigned short*)take(SD * 2);
  unsigned short* WqkvT = (unsigned short*)take((size_t)3072 * 1024 * 2);
  unsigned short* WoT   = (unsigned short*)take((size_t)1024 * 1024 * 2);
  unsigned short* v_t   = (unsigned short*)take(SD * 2);   // [B][D][S] fp16
  unsigned short* attn  = (unsigned short*)take(SD * 2);   // [B*S][D] fp16
  const size_t SC_B = (size_t)2048 * 2048;  // score elements per batch
  float* scores = (float*)take(4 * SC_B * 4);  // P fp16 aliased in-place

  dim3 blk(256), blk5(512);
  k_convert_f16<<<dim3(8192), blk, 0, stream>>>(x, x_h, (int)(SD / 4));
  k_transpose_f16<<<dim3(32, 32), blk, 0, stream>>>(Wq, WqkvT, 1024);
  k_transpose_f16<<<dim3(32, 32), blk, 0, stream>>>(Wk, WqkvT + (size_t)1024 * 1024, 1024);
  k_transpose_f16<<<dim3(32, 32), blk, 0, stream>>>(Wv, WqkvT + (size_t)2048 * 1024, 1024);
  k_transpose_f16<<<dim3(32, 32), blk, 0, stream>>>(Wo, WoT, 1024);

  // fused QKV projection: [8192 x 1024] x [3072 x 1024]^T, 256^2 tiles
  k_gemm8<0><<<dim3(32, 12, 1), blk5, 0, stream>>>(
      x_h, WqkvT, 8, 1024, 1024, 0, 0, 0,
      bq, bk, bv, nullptr, q_h, k_h, v_t, 0);

  const size_t QZS = (size_t)2048 * 1024;   // q/k batch stride (elements)
  const size_t VZS = (size_t)1024 * 2048;   // v_t batch stride
  const size_t PZS = SC_B * 2;              // P batch stride (fp16, aliased rows)
  // scores = q . k^T  (fp32 out), all 4 batches, 256^2 tiles
  k_gemm8<2><<<dim3(8, 8, 4), blk5, 0, stream>>>(
      q_h, k_h, 8, 1024, 1024, QZS, QZS, SC_B,
      nullptr, nullptr, nullptr, scores, nullptr, nullptr, nullptr, 2048);
  // softmax in-place (P fp16 overwrites score rows)
  k_softmax<<<dim3(8192), blk, 0, stream>>>(scores, (unsigned short*)scores);
  // attn = P . V   (P has ldA=4096 fp16 elements due to in-place aliasing)
  k_gemm_s<3><<<dim3(16, 8, 4), blk, 0, stream>>>(
      (const unsigned short*)scores, v_t, 2048, 4096, 2048, PZS, VZS, QZS,
      nullptr, nullptr, nullptr, attn, 1024);
  // out = attn . Wo^T + bo + x
  k_gemm_s<4><<<dim3(64, 8, 1), blk, 0, stream>>>(
      attn, WoT, 1024, 1024, 1024, 0, 0, 0,
      bo, x, out, nullptr, 1024);
}